// Round 7
// baseline (407.001 us; speedup 1.0000x reference)
//
#include <hip/hip_runtime.h>
#include <math.h>

#define NUM_TREES 20000
#define MAX_DEPTH 8
#define MAX_SIZE  40
#define VOCAB     30000
#define DIM       128
#define TOT       (MAX_DEPTH * MAX_SIZE)       // 320 tokens per tree
#define NTILE     8
#define TILE_ROWS (VOCAB / NTILE)              // 3750 rows = 1.92 MB (L2-resident)
#define TPA       4                            // trees per block (wave per tree)

typedef unsigned long long ull;

__device__ __forceinline__ double waveSumD(double v) {
    v += __shfl_xor(v, 32);
    v += __shfl_xor(v, 16);
    v += __shfl_xor(v, 8);
    v += __shfl_xor(v, 4);
    v += __shfl_xor(v, 2);
    v += __shfl_xor(v, 1);
    return v;
}

// One packed butterfly for three independent fp64 sums (ILP hides the
// per-step shuffle latency across the three chains).
__device__ __forceinline__ void waveSum3(double& a, double& b, double& c) {
    #pragma unroll
    for (int m = 32; m >= 1; m >>= 1) {
        a += __shfl_xor(a, m);
        b += __shfl_xor(b, m);
        c += __shfl_xor(c, m);
    }
}

// masks may arrive as 1-byte bool or int32; probe word 0 (all-ones input:
// byte layout reads 0x01010101, int32 layout reads 0x00000001).
__device__ __forceinline__ int loadMask(const void* m, size_t idx, bool asByte) {
    return asByte ? (int)((const unsigned char*)m)[idx] : ((const int*)m)[idx];
}

// Phase 0: ts[v] = dot(embedding[v], context_weight) in fp64 (one wave per row)
__global__ __launch_bounds__(256) void tokscore_kernel(
        const float* __restrict__ emb, const float* __restrict__ cw,
        double* __restrict__ ts) {
    int row  = (blockIdx.x * blockDim.x + threadIdx.x) >> 6;
    int lane = threadIdx.x & 63;
    if (row >= VOCAB) return;
    float2 e2 = *(const float2*)(emb + (size_t)row * DIM + lane * 2);
    float2 w2 = *(const float2*)(cw + lane * 2);
    double p = (double)e2.x * (double)w2.x + (double)e2.y * (double)w2.y;
    p = waveSumD(p);
    if (lane == 0) ts[row] = p;
}

// Fused kernel: wave-per-tree fp64 recursion (registers, round-5-validated),
// ballot counting-sort of (coef,tok) pairs into LDS (tile-major order), then
// a single half-wave float4 gather over the sorted list. Tile-sorting exists
// purely for cross-block L2 locality: all resident blocks walk vocab tiles
// in the same order, keeping ~2 tiles (<4MB) hot per XCD L2.
// (256,4): validated no-spill config (round 6's (256,6) spilled: +207MB traffic).
__global__ __launch_bounds__(256, 4) void fused_kernel(
        const int* __restrict__ tokens, const void* __restrict__ masks,
        const double* __restrict__ ts, const float* __restrict__ emb,
        float* __restrict__ out) {
    __shared__ ull l_pair[TPA][TOT];   // 10 KB, tile-sorted pairs per tree

    const int tid  = threadIdx.x;
    const int w    = tid >> 6;          // wave id = local tree index
    const int s    = tid & 63;          // lane = sibling position
    const int tree = blockIdx.x * TPA + w;
    const size_t base = (size_t)tree * TOT;
    const bool mByte = (((const int*)masks)[0] != 1);   // see loadMask comment
    const bool inS = s < MAX_SIZE;

    // ---- per-wave load: tokens/masks/scores into registers.
    int    tok[MAX_DEPTH];
    double e[MAX_DEPTH];
    unsigned int valbit = 0, mskbit = 0;
    #pragma unroll
    for (int d = 0; d < MAX_DEPTH; ++d) {
        int t = -1, m = 0;
        if (inS) {
            t = tokens[base + d * MAX_SIZE + s];
            m = loadMask(masks, base + d * MAX_SIZE + s, mByte);
        }
        tok[d] = t < 0 ? 0 : t;
        e[d]   = inS ? ts[tok[d]] : 0.0;
        if (inS && m != 0) mskbit |= 1u << d;
        if (inS && m != 0 && t >= 0) valbit |= 1u << d;
    }
    unsigned int childbit = 0;
    #pragma unroll
    for (int d = 0; d < MAX_DEPTH - 1; ++d) {
        ull bal = __ballot((mskbit >> (d + 1)) & 1u);
        int nc = (int)__popcll(bal);
        if (nc < 1) nc = 1;
        if (((valbit >> d) & 1u) && s < nc) childbit |= 1u << d;
    }

    // ---- recursion (math identical to validated rounds 4-6; HW f32 exp:
    // rel err ~1e-7, cancels in the softmax ratio).
    double v7 = ((valbit >> 7) & 1u) ? 1.0 : 0.0;
    double pw = waveSumD(e[7] * v7);

    float  attnf[MAX_DEPTH - 1];
    double cArr[MAX_DEPTH - 1];
    #pragma unroll
    for (int d = MAX_DEPTH - 2; d >= 0; --d) {
        float  gf = 1.0f / (1.0f + __expf((float)(-e[d])));
        double cf = ((childbit >> d) & 1u) ? (double)gf : 0.0;  // gate*child
        double a  = fma(cf, pw, e[d]);
        double ex = ((valbit >> d) & 1u) ? (double)__expf((float)a) : 0.0;
        double s0 = ex;            // -> den
        double s1 = ex * cf;       // -> c * den
        double s2 = ex * e[d];     // -> (sum attn*e) * den
        waveSum3(s0, s1, s2);
        double inv = 1.0 / s0;
        double c   = s1 * inv;
        pw = fma(c, pw, s2 * inv);
        attnf[d] = (float)(ex * inv);   // attn
        cArr[d]  = c;
    }
    float coef[MAX_DEPTH];
    double prefix = 1.0;
    #pragma unroll
    for (int d = 0; d <= MAX_DEPTH - 2; ++d) {
        coef[d] = (float)(prefix * (double)attnf[d]);
        prefix *= cArr[d];
    }
    coef[MAX_DEPTH - 1] = (float)(prefix * v7);

    // ---- ballot-based counting sort by vocab tile -> LDS (register-only
    // bookkeeping; all indices compile-time after unroll).
    int tl[MAX_DEPTH];
    unsigned int nzbit = 0;
    #pragma unroll
    for (int d = 0; d < MAX_DEPTH; ++d) {
        tl[d] = tok[d] / TILE_ROWS;
        if (coef[d] != 0.0f) nzbit |= 1u << d;
    }
    const ull ltm = (1ull << s) - 1ull;    // lanes below me

    int cnt[NTILE];
    #pragma unroll
    for (int t = 0; t < NTILE; ++t) cnt[t] = 0;
    #pragma unroll
    for (int d = 0; d < MAX_DEPTH; ++d) {
        bool nz = (nzbit >> d) & 1u;
        #pragma unroll
        for (int t = 0; t < NTILE; ++t)
            cnt[t] += (int)__popcll(__ballot(nz && tl[d] == t));
    }
    int hoff[NTILE + 1];
    hoff[0] = 0;
    #pragma unroll
    for (int t = 0; t < NTILE; ++t) hoff[t + 1] = hoff[t] + cnt[t];

    int ridx[NTILE];
    #pragma unroll
    for (int t = 0; t < NTILE; ++t) ridx[t] = hoff[t];
    #pragma unroll
    for (int d = 0; d < MAX_DEPTH; ++d) {
        bool nz = (nzbit >> d) & 1u;
        int slot = -1;
        #pragma unroll
        for (int t = 0; t < NTILE; ++t) {
            ull m = __ballot(nz && tl[d] == t);
            if (nz && tl[d] == t) slot = ridx[t] + (int)__popcll(m & ltm);
            ridx[t] += (int)__popcll(m);
        }
        if (slot >= 0)
            l_pair[w][slot] =
                ((ull)__float_as_uint(coef[d]) << 32) | (ull)(unsigned)tok[d];
    }
    // nTot is wave-uniform (popcll of ballots); scalarize for loop bounds.
    const int nTot = __builtin_amdgcn_readfirstlane(hoff[NTILE]);

    // ---- gather over the tile-sorted list (wave-local LDS: same wave wrote
    // it, compiler's lgkmcnt ordering suffices; no barrier). Half-wave trick:
    // lanes 0-31 take the even row, 32-63 the odd row; each lane a float4
    // column slice -> one global_load_dwordx4 covers TWO 512B rows.
    const bool hi = s >= 32;
    const int  cb = (s & 31) << 2;         // column base (floats)
    float a0 = 0.0f, a1 = 0.0f, a2 = 0.0f, a3 = 0.0f;

    int j = 0;
    for (; j + 8 <= nTot; j += 8) {        // 8 rows = 4 dwordx4 loads in flight
        uint4 q0 = *(const uint4*)&l_pair[w][j + 0];
        uint4 q1 = *(const uint4*)&l_pair[w][j + 2];
        uint4 q2 = *(const uint4*)&l_pair[w][j + 4];
        uint4 q3 = *(const uint4*)&l_pair[w][j + 6];
        unsigned tk0 = hi ? q0.z : q0.x;  float w0 = __uint_as_float(hi ? q0.w : q0.y);
        unsigned tk1 = hi ? q1.z : q1.x;  float w1 = __uint_as_float(hi ? q1.w : q1.y);
        unsigned tk2 = hi ? q2.z : q2.x;  float w2 = __uint_as_float(hi ? q2.w : q2.y);
        unsigned tk3 = hi ? q3.z : q3.x;  float w3 = __uint_as_float(hi ? q3.w : q3.y);
        const float4 v0 = *(const float4*)(emb + (size_t)tk0 * DIM + cb);
        const float4 v1 = *(const float4*)(emb + (size_t)tk1 * DIM + cb);
        const float4 v2 = *(const float4*)(emb + (size_t)tk2 * DIM + cb);
        const float4 v3 = *(const float4*)(emb + (size_t)tk3 * DIM + cb);
        a0 = fmaf(w0, v0.x, a0); a1 = fmaf(w0, v0.y, a1);
        a2 = fmaf(w0, v0.z, a2); a3 = fmaf(w0, v0.w, a3);
        a0 = fmaf(w1, v1.x, a0); a1 = fmaf(w1, v1.y, a1);
        a2 = fmaf(w1, v1.z, a2); a3 = fmaf(w1, v1.w, a3);
        a0 = fmaf(w2, v2.x, a0); a1 = fmaf(w2, v2.y, a1);
        a2 = fmaf(w2, v2.z, a2); a3 = fmaf(w2, v2.w, a3);
        a0 = fmaf(w3, v3.x, a0); a1 = fmaf(w3, v3.y, a1);
        a2 = fmaf(w3, v3.z, a2); a3 = fmaf(w3, v3.w, a3);
    }
    for (; j + 2 <= nTot; j += 2) {
        uint4 q = *(const uint4*)&l_pair[w][j];
        unsigned tk = hi ? q.z : q.x;
        float    wt = __uint_as_float(hi ? q.w : q.y);
        const float4 v = *(const float4*)(emb + (size_t)tk * DIM + cb);
        a0 = fmaf(wt, v.x, a0); a1 = fmaf(wt, v.y, a1);
        a2 = fmaf(wt, v.z, a2); a3 = fmaf(wt, v.w, a3);
    }
    if (j < nTot) {                        // single leftover row: upper half
        ull pr = l_pair[w][j];             // contributes 0
        unsigned tk = (unsigned)pr;
        float    wt = hi ? 0.0f : __uint_as_float((unsigned)(pr >> 32));
        const float4 v = *(const float4*)(emb + (size_t)tk * DIM + cb);
        a0 = fmaf(wt, v.x, a0); a1 = fmaf(wt, v.y, a1);
        a2 = fmaf(wt, v.z, a2); a3 = fmaf(wt, v.w, a3);
    }

    // Combine half-waves (lane i and i+32 hold the same columns).
    a0 += __shfl_xor(a0, 32);
    a1 += __shfl_xor(a1, 32);
    a2 += __shfl_xor(a2, 32);
    a3 += __shfl_xor(a3, 32);

    if (s < 32) {
        float* op = out + (size_t)tree * DIM + cb;
        *(float4*)op = make_float4(a0, a1, a2, a3);   // single write, no RMW
    }
}

extern "C" void kernel_launch(void* const* d_in, const int* in_sizes, int n_in,
                              void* d_out, int out_size, void* d_ws, size_t ws_size,
                              hipStream_t stream) {
    const int*   tokens = (const int*)d_in[0];
    const void*  masks  = d_in[1];
    const float* emb    = (const float*)d_in[2];
    const float* cw     = (const float*)d_in[3];
    float*       out    = (float*)d_out;
    double*      ts     = (double*)d_ws;   // 30000 doubles = 240 KB scratch

    int ts_blocks = (VOCAB * 64 + 255) / 256;   // one wave per vocab row
    tokscore_kernel<<<ts_blocks, 256, 0, stream>>>(emb, cw, ts);
    fused_kernel<<<NUM_TREES / TPA, 256, 0, stream>>>(tokens, masks, ts, emb, out);
}